// Round 1
// baseline (5962.574 us; speedup 1.0000x reference)
//
#include <hip/hip_runtime.h>

// Problem: B=64, S=512, I=256, O=256, fp32 LSTM.
// out = [h_seq (64*512*256)] [hT (64*256)] [cT (64*256)]
//
// Phase A: xg[b][t][g*256+p] = sum_i x[b][t][i]*Wx[g][p][i] + bx[g][p] + bh[g][p]
//          (plain fp32 LDS-tiled GEMM, M=32768 N=1024 K=256)
// Phase B: persistent scan. 32 batch-groups x 2 batches, 8 blocks per group.
//          Each block holds a 128-column slice of Wh in LDS (130 KB) and owns
//          p in [member*32, member*32+32) for all 4 gates. Per step: stage h
//          (2 batches) into LDS, accumulate partial dots (o split 2-way across
//          threads), block-local reduce, gate nonlinearity, publish h slice to
//          global double-buffer + flag (agent-scope atomics), spin on group
//          flags for next step. 256 blocks, 1 per CU, all co-resident.

#define SS 512
#define BB 64

// ---------------------------------------------------------------- Phase A
__global__ __launch_bounds__(256) void xg_gemm(
    const float* __restrict__ X,   // [32768][256]
    const float* __restrict__ W,   // [1024][256]  (Wx flat)
    const float* __restrict__ bx,  // [1024]
    const float* __restrict__ bh,  // [1024]
    float* __restrict__ out)       // [32768][1024]
{
  __shared__ float As[64][68];   // [m][k]  (rows padded: 68)
  __shared__ float Bs[64][68];   // [k][n]  (transposed W tile)
  const int bm = blockIdx.x >> 4;
  const int bn = blockIdx.x & 15;
  const int tid = threadIdx.x;
  const int tn = tid & 15, tm = tid >> 4;
  const int row0 = bm * 64, col0 = bn * 64;
  float acc[4][4] = {};

  for (int k0 = 0; k0 < 256; k0 += 64) {
#pragma unroll
    for (int i = 0; i < 4; i++) {
      const int m = (tid >> 4) + i * 16;
      const int k = (tid & 15) * 4;
      float4 av = *(const float4*)&X[(size_t)(row0 + m) * 256 + k0 + k];
      *(float4*)&As[m][k] = av;
      float4 wv = *(const float4*)&W[(size_t)(col0 + m) * 256 + k0 + k];
      Bs[k + 0][m] = wv.x; Bs[k + 1][m] = wv.y;
      Bs[k + 2][m] = wv.z; Bs[k + 3][m] = wv.w;
    }
    __syncthreads();
#pragma unroll 8
    for (int kk = 0; kk < 64; kk++) {
      const float a0 = As[tm * 4 + 0][kk];
      const float a1 = As[tm * 4 + 1][kk];
      const float a2 = As[tm * 4 + 2][kk];
      const float a3 = As[tm * 4 + 3][kk];
      const float4 bv = *(const float4*)&Bs[kk][tn * 4];
      acc[0][0] = fmaf(a0, bv.x, acc[0][0]); acc[0][1] = fmaf(a0, bv.y, acc[0][1]);
      acc[0][2] = fmaf(a0, bv.z, acc[0][2]); acc[0][3] = fmaf(a0, bv.w, acc[0][3]);
      acc[1][0] = fmaf(a1, bv.x, acc[1][0]); acc[1][1] = fmaf(a1, bv.y, acc[1][1]);
      acc[1][2] = fmaf(a1, bv.z, acc[1][2]); acc[1][3] = fmaf(a1, bv.w, acc[1][3]);
      acc[2][0] = fmaf(a2, bv.x, acc[2][0]); acc[2][1] = fmaf(a2, bv.y, acc[2][1]);
      acc[2][2] = fmaf(a2, bv.z, acc[2][2]); acc[2][3] = fmaf(a2, bv.w, acc[2][3]);
      acc[3][0] = fmaf(a3, bv.x, acc[3][0]); acc[3][1] = fmaf(a3, bv.y, acc[3][1]);
      acc[3][2] = fmaf(a3, bv.z, acc[3][2]); acc[3][3] = fmaf(a3, bv.w, acc[3][3]);
    }
    __syncthreads();
  }

  float bias[4];
#pragma unroll
  for (int j = 0; j < 4; j++) {
    const int col = col0 + tn * 4 + j;
    bias[j] = bx[col] + bh[col];
  }
#pragma unroll
  for (int i = 0; i < 4; i++) {
    float4 o4;
    o4.x = acc[i][0] + bias[0]; o4.y = acc[i][1] + bias[1];
    o4.z = acc[i][2] + bias[2]; o4.w = acc[i][3] + bias[3];
    *(float4*)&out[(size_t)(row0 + tm * 4 + i) * 1024 + col0 + tn * 4] = o4;
  }
}

// ---------------------------------------------------------------- Phase B
__global__ __launch_bounds__(256) void lstm_scan(
    const float* __restrict__ xg,   // [64][512][1024]
    const float* __restrict__ Wh,   // [1024][256] flat ([g][p][o])
    const float* __restrict__ h0,   // [64][256]
    const float* __restrict__ c0,   // [64][256]
    float* __restrict__ out,        // h_seq | hT | cT
    float* hbuf,                    // [2][32][2][256] parity double buffer
    int* flags)                     // [32][8] stride-16 ints (poison < 0 ok)
{
  __shared__ float w_lds[128][260];   // [local col][o], 260 = 256 + 4 pad
  __shared__ float2 h_st[256];        // [o] -> (h[b0], h[b1])
  __shared__ float part[2][128][2];   // [o-half][local col][batch]
  __shared__ float c_st[2][32];       // [batch][p_local]

  const int tid = threadIdx.x;
  const int group = blockIdx.x & 31;   // 32 groups of 2 batches
  const int member = blockIdx.x >> 5;  // 8 p-slices
  const int p_base = member * 32;
  const int b0 = group * 2;

  // Load Wh slice: local col cc = g*32 + pl  ->  global row g*256 + p_base + pl
  for (int idx = tid; idx < 128 * 256; idx += 256) {
    const int cc = idx >> 8;
    const int o = idx & 255;
    const int g = cc >> 5, pl = cc & 31;
    w_lds[cc][o] = Wh[(size_t)(g * 256 + p_base + pl) * 256 + o];
  }
  if (tid < 64) {
    const int bl = tid >> 5, pl = tid & 31;
    c_st[bl][pl] = c0[(size_t)(b0 + bl) * 256 + p_base + pl];
  }
  __syncthreads();

  const int c = tid & 127;
  const int oh = tid >> 7;
  const int ob = oh << 7;
  const float* wrow = &w_lds[c][ob];

  for (int t = 0; t < SS; t++) {
    // ---- stage h(t-1) into LDS
    if (t == 0) {
      for (int idx = tid; idx < 512; idx += 256) {
        const int bl = idx & 1, o = idx >> 1;
        ((float*)h_st)[idx] = h0[(size_t)(b0 + bl) * 256 + o];
      }
    } else {
      if (tid < 8) {
        while (__hip_atomic_load(&flags[(group * 8 + tid) * 16],
                                 __ATOMIC_ACQUIRE, __HIP_MEMORY_SCOPE_AGENT) < t) {
          __builtin_amdgcn_s_sleep(2);
        }
      }
      __syncthreads();
      const float* hb = hbuf + (size_t)(((t - 1) & 1) * 32 + group) * 512;
      for (int idx = tid; idx < 512; idx += 256) {
        const int bl = idx & 1, o = idx >> 1;
        ((float*)h_st)[idx] = __hip_atomic_load(&hb[bl * 256 + o],
                                                __ATOMIC_RELAXED, __HIP_MEMORY_SCOPE_AGENT);
      }
    }
    __syncthreads();

    // ---- partial dots over this thread's o-half
    float a0 = 0.f, a1 = 0.f;
#pragma unroll
    for (int j = 0; j < 128; j += 4) {
      const float4 wv = *(const float4*)&wrow[j];
      const float4 hAB = *(const float4*)&h_st[ob + j];      // h[j](b0,b1), h[j+1](b0,b1)
      const float4 hCD = *(const float4*)&h_st[ob + j + 2];  // h[j+2], h[j+3]
      a0 = fmaf(wv.x, hAB.x, a0); a1 = fmaf(wv.x, hAB.y, a1);
      a0 = fmaf(wv.y, hAB.z, a0); a1 = fmaf(wv.y, hAB.w, a1);
      a0 = fmaf(wv.z, hCD.x, a0); a1 = fmaf(wv.z, hCD.y, a1);
      a0 = fmaf(wv.w, hCD.z, a0); a1 = fmaf(wv.w, hCD.w, a1);
    }
    *(float2*)&part[oh][c][0] = make_float2(a0, a1);
    __syncthreads();

    // ---- reduce + gates + publish (64 threads: 2 batches x 32 p)
    if (tid < 64) {
      const int bl = tid >> 5, pl = tid & 31;
      const int b = b0 + bl;
      const float* xr = xg + ((size_t)b * SS + t) * 1024 + p_base + pl;
      const float y0 = part[0][pl][bl]      + part[1][pl][bl]      + xr[0];
      const float y1 = part[0][32 + pl][bl] + part[1][32 + pl][bl] + xr[256];
      const float y2 = part[0][64 + pl][bl] + part[1][64 + pl][bl] + xr[512];
      const float y3 = part[0][96 + pl][bl] + part[1][96 + pl][bl] + xr[768];
      const float fg = 1.f / (1.f + __expf(-y0));
      const float ig = 1.f / (1.f + __expf(-y1));
      const float gt = tanhf(y2);
      const float og = 1.f / (1.f + __expf(-y3));
      const float cn = c_st[bl][pl] * fg + ig * gt;
      c_st[bl][pl] = cn;
      const float h = og * tanhf(cn);
      out[(size_t)b * (SS * 256) + (size_t)t * 256 + p_base + pl] = h;
      float* hb = hbuf + (size_t)((t & 1) * 32 + group) * 512;
      __hip_atomic_store(&hb[bl * 256 + p_base + pl], h,
                         __ATOMIC_RELAXED, __HIP_MEMORY_SCOPE_AGENT);
      if (t == SS - 1) {
        out[8388608 + (size_t)b * 256 + p_base + pl] = h;            // hT
        out[8388608 + 16384 + (size_t)b * 256 + p_base + pl] = cn;   // cT
      }
    }
    __syncthreads();
    if (tid == 0) {
      __threadfence();
      __hip_atomic_store(&flags[(group * 8 + member) * 16], t + 1,
                         __ATOMIC_RELEASE, __HIP_MEMORY_SCOPE_AGENT);
    }
  }
}

// ---------------------------------------------------------------- launch
extern "C" void kernel_launch(void* const* d_in, const int* in_sizes, int n_in,
                              void* d_out, int out_size, void* d_ws, size_t ws_size,
                              hipStream_t stream) {
  const float* x  = (const float*)d_in[0];
  const float* h0 = (const float*)d_in[1];
  const float* c0 = (const float*)d_in[2];
  const float* Wh = (const float*)d_in[3];
  const float* bh = (const float*)d_in[4];
  const float* Wx = (const float*)d_in[5];
  const float* bx = (const float*)d_in[6];
  float* out = (float*)d_out;

  float* xg   = (float*)d_ws;                       // 32768*1024 floats = 128 MB
  float* hbuf = xg + (size_t)32768 * 1024;          // 2*32*512 floats
  int* flags  = (int*)(hbuf + 2 * 32 * 512);        // 32*8*16 ints

  xg_gemm<<<dim3(8192), dim3(256), 0, stream>>>(x, Wx, bx, bh, xg);
  lstm_scan<<<dim3(256), dim3(256), 0, stream>>>(xg, Wh, h0, c0, out, hbuf, flags);
}

// Round 2
// 1238.765 us; speedup vs baseline: 4.8133x; 4.8133x over previous
//
#include <hip/hip_runtime.h>

// B=64, S=512, I=256, O=256 fp32 LSTM.
// out = [h_seq (64*512*256)] [hT (64*256)] [cT (64*256)]
//
// Phase A: xg = x @ Wx^T + bx + bh  (fp32 LDS-tiled GEMM, unchanged from R1)
// Phase B: one block per batch (64 blocks, 512 threads). Wh converted to fp16
//   and held entirely on-CU: 96 half2 per output row in VGPRs (192 persistent
//   VGPRs) + 32 half2 per row in LDS (128 KB). h(t) staged in LDS as fp16;
//   fp32 accumulation via v_dot2_f32_f16. Zero inter-block communication.

#define SS 512

typedef _Float16 h2 __attribute__((ext_vector_type(2)));

__device__ __forceinline__ h2 bch(unsigned u) { return __builtin_bit_cast(h2, u); }

#if __has_builtin(__builtin_amdgcn_fdot2)
__device__ __forceinline__ float dot2f(h2 a, h2 b, float c) {
  return __builtin_amdgcn_fdot2(a, b, c, false);
}
#else
__device__ __forceinline__ float dot2f(h2 a, h2 b, float c) {
  return c + (float)a[0] * (float)b[0] + (float)a[1] * (float)b[1];
}
#endif

__device__ __forceinline__ float sigm(float x) { return 1.f / (1.f + __expf(-x)); }
__device__ __forceinline__ float tanh_f(float x) {
  float e = __expf(-2.f * fabsf(x));      // e in (0,1], no overflow
  float r = (1.f - e) / (1.f + e);
  return copysignf(r, x);
}

// ---------------------------------------------------------------- Phase A
__global__ __launch_bounds__(256) void xg_gemm(
    const float* __restrict__ X, const float* __restrict__ W,
    const float* __restrict__ bx, const float* __restrict__ bh,
    float* __restrict__ out)
{
  __shared__ float As[64][68];
  __shared__ float Bs[64][68];
  const int bm = blockIdx.x >> 4;
  const int bn = blockIdx.x & 15;
  const int tid = threadIdx.x;
  const int tn = tid & 15, tm = tid >> 4;
  const int row0 = bm * 64, col0 = bn * 64;
  float acc[4][4] = {};

  for (int k0 = 0; k0 < 256; k0 += 64) {
#pragma unroll
    for (int i = 0; i < 4; i++) {
      const int m = (tid >> 4) + i * 16;
      const int k = (tid & 15) * 4;
      float4 av = *(const float4*)&X[(size_t)(row0 + m) * 256 + k0 + k];
      *(float4*)&As[m][k] = av;
      float4 wv = *(const float4*)&W[(size_t)(col0 + m) * 256 + k0 + k];
      Bs[k + 0][m] = wv.x; Bs[k + 1][m] = wv.y;
      Bs[k + 2][m] = wv.z; Bs[k + 3][m] = wv.w;
    }
    __syncthreads();
#pragma unroll 8
    for (int kk = 0; kk < 64; kk++) {
      const float a0 = As[tm * 4 + 0][kk];
      const float a1 = As[tm * 4 + 1][kk];
      const float a2 = As[tm * 4 + 2][kk];
      const float a3 = As[tm * 4 + 3][kk];
      const float4 bv = *(const float4*)&Bs[kk][tn * 4];
      acc[0][0] = fmaf(a0, bv.x, acc[0][0]); acc[0][1] = fmaf(a0, bv.y, acc[0][1]);
      acc[0][2] = fmaf(a0, bv.z, acc[0][2]); acc[0][3] = fmaf(a0, bv.w, acc[0][3]);
      acc[1][0] = fmaf(a1, bv.x, acc[1][0]); acc[1][1] = fmaf(a1, bv.y, acc[1][1]);
      acc[1][2] = fmaf(a1, bv.z, acc[1][2]); acc[1][3] = fmaf(a1, bv.w, acc[1][3]);
      acc[2][0] = fmaf(a2, bv.x, acc[2][0]); acc[2][1] = fmaf(a2, bv.y, acc[2][1]);
      acc[2][2] = fmaf(a2, bv.z, acc[2][2]); acc[2][3] = fmaf(a2, bv.w, acc[2][3]);
      acc[3][0] = fmaf(a3, bv.x, acc[3][0]); acc[3][1] = fmaf(a3, bv.y, acc[3][1]);
      acc[3][2] = fmaf(a3, bv.z, acc[3][2]); acc[3][3] = fmaf(a3, bv.w, acc[3][3]);
    }
    __syncthreads();
  }

  float bias[4];
#pragma unroll
  for (int j = 0; j < 4; j++) {
    const int col = col0 + tn * 4 + j;
    bias[j] = bx[col] + bh[col];
  }
#pragma unroll
  for (int i = 0; i < 4; i++) {
    float4 o4;
    o4.x = acc[i][0] + bias[0]; o4.y = acc[i][1] + bias[1];
    o4.z = acc[i][2] + bias[2]; o4.w = acc[i][3] + bias[3];
    *(float4*)&out[(size_t)(row0 + tm * 4 + i) * 1024 + col0 + tn * 4] = o4;
  }
}

// ---------------------------------------------------------------- Phase B
// Thread tid owns gate rows p0=tid (gate f if tid<256 else i) and p1=tid+512
// (gate g if tid<256 else o). k in [0,192) from VGPR-resident fp16 weights,
// k in [192,256) from LDS-resident fp16 weights.
__global__ __launch_bounds__(512, 2) void lstm_scan2(
    const float* __restrict__ xg,   // [64][512][1024]
    const float* __restrict__ Wh,   // [1024][256]
    const float* __restrict__ h0,   // [64][256]
    const float* __restrict__ c0,   // [64][256]
    float* __restrict__ out)
{
  // wl layout: [o(2)][chunk(8)][tid(512)][8 halves] -> contiguous 16B per lane
  __shared__ __align__(16) _Float16 wl[2 * 8 * 512 * 8];   // 128 KB
  __shared__ __align__(16) _Float16 h_sh[256];
  __shared__ float io_i[256];
  __shared__ float io_o[256];

  const int tid = threadIdx.x;
  const int b = blockIdx.x;

  const float* r0 = Wh + (size_t)tid * 256;
  const float* r1 = Wh + (size_t)(tid + 512) * 256;

  // ---- persistent register weights: k in [0,192) as 96 half2 per output
  h2 w0[96], w1[96];
#pragma unroll
  for (int j = 0; j < 96; ++j) {
    float2 a = *(const float2*)&r0[2 * j];
    float2 c = *(const float2*)&r1[2 * j];
    h2 wa; wa[0] = (_Float16)a.x; wa[1] = (_Float16)a.y; w0[j] = wa;
    h2 wc; wc[0] = (_Float16)c.x; wc[1] = (_Float16)c.y; w1[j] = wc;
  }
  // ---- LDS weights: k in [192,256)
#pragma unroll
  for (int c = 0; c < 8; ++c) {
#pragma unroll
    for (int e = 0; e < 8; ++e) {
      wl[((size_t)(c)*512 + tid) * 8 + e]     = (_Float16)r0[192 + c * 8 + e];
      wl[((size_t)(8 + c)*512 + tid) * 8 + e] = (_Float16)r1[192 + c * 8 + e];
    }
  }
  // ---- initial state
  if (tid < 256) h_sh[tid] = (_Float16)h0[(size_t)b * 256 + tid];
  float cr = (tid < 256) ? c0[(size_t)b * 256 + tid] : 0.f;
  __syncthreads();

  const float* xr = xg + (size_t)b * SS * 1024;
  float* hs = out + (size_t)b * SS * 256;

  for (int t = 0; t < SS; ++t) {
    const float xg0 = xr[(size_t)t * 1024 + tid];
    const float xg1 = xr[(size_t)t * 1024 + tid + 512];

    float A0 = 0.f, B0 = 0.f, A1 = 0.f, B1 = 0.f;
#pragma unroll
    for (int c2 = 0; c2 < 12; ++c2) {
      uint4 ha = *(const uint4*)&h_sh[c2 * 16];
      uint4 hb = *(const uint4*)&h_sh[c2 * 16 + 8];
      const int j = c2 * 8;
      A0 = dot2f(w0[j + 0], bch(ha.x), A0); A1 = dot2f(w1[j + 0], bch(ha.x), A1);
      B0 = dot2f(w0[j + 1], bch(ha.y), B0); B1 = dot2f(w1[j + 1], bch(ha.y), B1);
      A0 = dot2f(w0[j + 2], bch(ha.z), A0); A1 = dot2f(w1[j + 2], bch(ha.z), A1);
      B0 = dot2f(w0[j + 3], bch(ha.w), B0); B1 = dot2f(w1[j + 3], bch(ha.w), B1);
      A0 = dot2f(w0[j + 4], bch(hb.x), A0); A1 = dot2f(w1[j + 4], bch(hb.x), A1);
      B0 = dot2f(w0[j + 5], bch(hb.y), B0); B1 = dot2f(w1[j + 5], bch(hb.y), B1);
      A0 = dot2f(w0[j + 6], bch(hb.z), A0); A1 = dot2f(w1[j + 6], bch(hb.z), A1);
      B0 = dot2f(w0[j + 7], bch(hb.w), B0); B1 = dot2f(w1[j + 7], bch(hb.w), B1);
    }
#pragma unroll
    for (int c = 0; c < 8; ++c) {
      uint4 hw = *(const uint4*)&h_sh[192 + c * 8];
      uint4 wa = *(const uint4*)&wl[((size_t)(c)*512 + tid) * 8];
      uint4 wb = *(const uint4*)&wl[((size_t)(8 + c)*512 + tid) * 8];
      A0 = dot2f(bch(wa.x), bch(hw.x), A0); A1 = dot2f(bch(wb.x), bch(hw.x), A1);
      B0 = dot2f(bch(wa.y), bch(hw.y), B0); B1 = dot2f(bch(wb.y), bch(hw.y), B1);
      A0 = dot2f(bch(wa.z), bch(hw.z), A0); A1 = dot2f(bch(wb.z), bch(hw.z), A1);
      B0 = dot2f(bch(wa.w), bch(hw.w), B0); B1 = dot2f(bch(wb.w), bch(hw.w), B1);
    }
    const float y0 = A0 + B0 + xg0;
    const float y1 = A1 + B1 + xg1;

    float u0 = 0.f, u1 = 0.f;
    if (tid < 256) {            // rows: f=tid, g=tid+512
      u0 = sigm(y0);
      u1 = tanh_f(y1);
    } else {                    // rows: i=tid-256+256, o=tid-256+768
      io_i[tid - 256] = sigm(y0);
      io_o[tid - 256] = sigm(y1);
    }
    __syncthreads();            // io visible; all dots done reading h_sh

    if (tid < 256) {
      cr = cr * u0 + io_i[tid] * u1;
      const float h = io_o[tid] * tanh_f(cr);
      hs[(size_t)t * 256 + tid] = h;
      h_sh[tid] = (_Float16)h;
      if (t == SS - 1) {
        out[8388608 + (size_t)b * 256 + tid] = h;            // hT
        out[8404992 + (size_t)b * 256 + tid] = cr;           // cT
      }
    }
    __syncthreads();            // h_sh ready for next step
  }
}

// ---------------------------------------------------------------- launch
extern "C" void kernel_launch(void* const* d_in, const int* in_sizes, int n_in,
                              void* d_out, int out_size, void* d_ws, size_t ws_size,
                              hipStream_t stream) {
  const float* x  = (const float*)d_in[0];
  const float* h0 = (const float*)d_in[1];
  const float* c0 = (const float*)d_in[2];
  const float* Wh = (const float*)d_in[3];
  const float* bh = (const float*)d_in[4];
  const float* Wx = (const float*)d_in[5];
  const float* bx = (const float*)d_in[6];
  float* out = (float*)d_out;

  float* xg = (float*)d_ws;   // 32768*1024 floats = 128 MB

  xg_gemm<<<dim3(8192), dim3(256), 0, stream>>>(x, Wx, bx, bh, xg);
  lstm_scan2<<<dim3(64), dim3(512), 0, stream>>>(xg, Wh, h0, c0, out);
}